// Round 1
// baseline (226.994 us; speedup 1.0000x reference)
//
#include <hip/hip_runtime.h>

// Head: fused single-head causal attention.
// B=4096 blocks, one per batch element. 256 threads = 4 waves.
// Wave w owns query rows [16w, 16w+16).
// All matmuls via v_mfma_f32_16x16x32_bf16.
//   A-frag: A[m = lane&15][k = quad*8 + j], 8 contiguous bf16 per lane.
//   B-frag: B[k = quad*8 + j][n = lane&15]  (so "B" source needs n-major, k-contiguous rows).
//   C/D   : col = lane&15, row = quad*4 + reg.   (all layouts HW-verified per guide §3/§5)

#define TT 64
#define CC 128
#define HD 32

typedef __bf16 bf16_t;
typedef __bf16 bf8_t __attribute__((ext_vector_type(8)));
typedef __bf16 bf4_t __attribute__((ext_vector_type(4)));
typedef float  f4_t  __attribute__((ext_vector_type(4)));

__global__ __launch_bounds__(256) void head_fused(
    const float* __restrict__ x, const float* __restrict__ Wq,
    const float* __restrict__ Wk, const float* __restrict__ Wv,
    float* __restrict__ out)
{
  // LDS budget: 17408 + 26112 + 5120 + 5120 + 4608 = 58368 B (< 64 KB static limit).
  // Row pads (+8 bf16) keep ds_read_b128 at <=2-way bank aliasing (free on gfx950, m136).
  __shared__ __align__(16) bf16_t xs[TT][136];   // x tile; re-used as ps[64][72] after phase 2
  __shared__ __align__(16) bf16_t wt[96][136];   // wt[n][k] = Wcat(k, n); n: 0-31 q, 32-63 k, 64-95 v
  __shared__ __align__(16) bf16_t qs[TT][40];    // q[row][d]
  __shared__ __align__(16) bf16_t ks[TT][40];    // k[row][d]  (B-frag source for QK^T)
  __shared__ __align__(16) bf16_t vt[HD][72];    // v^T[d][row] (B-frag source for PV)

  const int tid  = threadIdx.x;
  const int wave = tid >> 6;
  const int lane = tid & 63;
  const int quad = lane >> 4;
  const int l16  = lane & 15;
  const int b    = blockIdx.x;

  // ---------------- Phase 1: stage x (fp32->bf16) and W^T into LDS ----------------
  const float4* x4 = (const float4*)(x + (size_t)b * (TT * CC));
  #pragma unroll
  for (int i = 0; i < 8; ++i) {
    int e = tid + i * 256;                 // 2048 float4 total, coalesced
    float4 f = x4[e];
    int fi = e << 2;
    int row = fi >> 7, col = fi & 127;
    bf4_t h = { (bf16_t)f.x, (bf16_t)f.y, (bf16_t)f.z, (bf16_t)f.w };
    *(bf4_t*)&xs[row][col] = h;
  }
  {
    const float* Ws[3] = { Wq, Wk, Wv };
    #pragma unroll
    for (int m = 0; m < 3; ++m) {
      const float* W = Ws[m];
      #pragma unroll
      for (int i = 0; i < 16; ++i) {
        int e = tid + i * 256;             // 4096 elements, coalesced reads (L2-resident)
        float wv_ = W[e];
        int k = e >> 5, n = e & 31;
        wt[m * 32 + n][k] = (bf16_t)wv_;   // transpose into n-major
      }
    }
  }
  __syncthreads();

  // ---------------- Phase 2: qkv = x @ [Wq|Wk|Wv] ----------------
  f4_t zero4 = {0.f, 0.f, 0.f, 0.f};
  f4_t acc[6];
  #pragma unroll
  for (int n = 0; n < 6; ++n) acc[n] = zero4;
  #pragma unroll
  for (int kk = 0; kk < 4; ++kk) {
    int k0 = kk * 32 + quad * 8;
    bf8_t a = *(const bf8_t*)&xs[wave * 16 + l16][k0];
    #pragma unroll
    for (int n = 0; n < 6; ++n) {
      bf8_t bb = *(const bf8_t*)&wt[n * 16 + l16][k0];
      acc[n] = __builtin_amdgcn_mfma_f32_16x16x32_bf16(a, bb, acc[n], 0, 0, 0);
    }
  }
  #pragma unroll
  for (int r = 0; r < 4; ++r) {
    int row = wave * 16 + quad * 4 + r;    // C/D: row = quad*4 + reg
    qs[row][l16]      = (bf16_t)acc[0][r];
    qs[row][16 + l16] = (bf16_t)acc[1][r];
    ks[row][l16]      = (bf16_t)acc[2][r];
    ks[row][16 + l16] = (bf16_t)acc[3][r];
    vt[l16][row]      = (bf16_t)acc[4][r];   // store v transposed for PV B-frags
    vt[16 + l16][row] = (bf16_t)acc[5][r];
  }
  __syncthreads();

  // ---------------- Phase 3: S = QK^T * scale, causal softmax -> P (bf16, in LDS) ----------
  bf16_t (*ps)[72] = (bf16_t(*)[72])&xs[0][0];   // alias: x tile is dead now
  f4_t sc[4];
  #pragma unroll
  for (int nt = 0; nt < 4; ++nt) sc[nt] = zero4;
  {
    bf8_t aq = *(const bf8_t*)&qs[wave * 16 + l16][quad * 8];  // K = 32 = one mfma
    #pragma unroll
    for (int nt = 0; nt < 4; ++nt) {
      if (nt <= wave) {                    // causal: skip fully-masked upper tiles
        bf8_t bk = *(const bf8_t*)&ks[nt * 16 + l16][quad * 8];
        sc[nt] = __builtin_amdgcn_mfma_f32_16x16x32_bf16(aq, bk, zero4, 0, 0, 0);
      }
    }
  }
  const float scale = 0.17677669529663687f;      // 1/sqrt(32)
  #pragma unroll
  for (int r = 0; r < 4; ++r) {
    int rl = quad * 4 + r;                 // row within the 16-row tile
    float vals[4];
    float vmax = -INFINITY;
    #pragma unroll
    for (int nt = 0; nt < 4; ++nt) {
      float v_ = -INFINITY;
      if (nt < wave)                         v_ = sc[nt][r] * scale;
      else if (nt == wave && l16 <= rl)      v_ = sc[nt][r] * scale;  // diagonal tile mask
      vals[nt] = v_;
      vmax = fmaxf(vmax, v_);
    }
    // row lives in one 16-lane group (same quad): butterfly over low 4 lane bits
    #pragma unroll
    for (int off = 1; off < 16; off <<= 1)
      vmax = fmaxf(vmax, __shfl_xor(vmax, off));
    float psum = 0.f;
    #pragma unroll
    for (int nt = 0; nt < 4; ++nt) {
      float p = (vals[nt] == -INFINITY) ? 0.f : __expf(vals[nt] - vmax);
      vals[nt] = p;
      psum += p;
    }
    #pragma unroll
    for (int off = 1; off < 16; off <<= 1)
      psum += __shfl_xor(psum, off);
    float inv = 1.0f / psum;               // psum >= 1 (diagonal elem survives)
    int row = wave * 16 + rl;
    #pragma unroll
    for (int nt = 0; nt < 4; ++nt)
      ps[row][nt * 16 + l16] = (bf16_t)(vals[nt] * inv);  // zeros fill masked region
  }
  __syncthreads();

  // ---------------- Phase 4: O = P @ V ----------------
  f4_t o0 = zero4, o1 = zero4;
  #pragma unroll
  for (int kk = 0; kk < 2; ++kk) {
    int k0 = kk * 32 + quad * 8;
    bf8_t ap  = *(const bf8_t*)&ps[wave * 16 + l16][k0];
    bf8_t bv0 = *(const bf8_t*)&vt[l16][k0];
    bf8_t bv1 = *(const bf8_t*)&vt[16 + l16][k0];
    o0 = __builtin_amdgcn_mfma_f32_16x16x32_bf16(ap, bv0, o0, 0, 0, 0);
    o1 = __builtin_amdgcn_mfma_f32_16x16x32_bf16(ap, bv1, o1, 0, 0, 0);
  }
  float* ob = out + (size_t)b * (TT * HD);
  #pragma unroll
  for (int r = 0; r < 4; ++r) {
    int row = wave * 16 + quad * 4 + r;
    ob[row * HD + l16]      = o0[r];       // 16 lanes -> 64 B contiguous per segment
    ob[row * HD + 16 + l16] = o1[r];
  }
}

extern "C" void kernel_launch(void* const* d_in, const int* in_sizes, int n_in,
                              void* d_out, int out_size, void* d_ws, size_t ws_size,
                              hipStream_t stream) {
  const float* x  = (const float*)d_in[0];
  const float* Wq = (const float*)d_in[1];
  const float* Wk = (const float*)d_in[2];
  const float* Wv = (const float*)d_in[3];
  float* out = (float*)d_out;
  int B = in_sizes[0] / (TT * CC);         // 4096
  head_fused<<<dim3(B), dim3(256), 0, stream>>>(x, Wq, Wk, Wv, out);
}

// Round 2
// 219.019 us; speedup vs baseline: 1.0364x; 1.0364x over previous
//
#include <hip/hip_runtime.h>

// Head: fused single-head causal attention. B=4096 blocks, 256 thr = 4 waves.
// Round 2: weights pre-converted to bf16 in MFMA B-frag order by a prep
// kernel into d_ws; main kernel loads them from global (L2-hot) instead of
// staging 26 KB of LDS per block. LDS 58368->32256 B => 5 blocks/CU (62.5%).
//
// mfma_f32_16x16x32_bf16 layouts (HW-verified, guide §3):
//   A-frag: A[m = lane&15][k = quad*8 + j]
//   B-frag: B[k = quad*8 + j][n = lane&15]
//   C/D   : col = lane&15, row = quad*4 + reg

#define TT 64
#define CC 128
#define HD 32

typedef __bf16 bf16_t;
typedef __bf16 bf8_t __attribute__((ext_vector_type(8)));
typedef __bf16 bf4_t __attribute__((ext_vector_type(4)));
typedef float  f4_t  __attribute__((ext_vector_type(4)));

// d_ws layout: wf[(n6*4 + kk)*64 + lane] is one 16-byte bf8 B-frag.
// n6 = 0..5 (q lo/hi, k lo/hi, v lo/hi 16-col tiles), kk = 0..3 (K blocks of 32).
// Element j of that frag = Wsel[(kk*32 + (lane>>4)*8 + j)][ (n6&1)*16 + (lane&15) ].
__global__ __launch_bounds__(256) void prep_weights(
    const float* __restrict__ Wq, const float* __restrict__ Wk,
    const float* __restrict__ Wv, bf16_t* __restrict__ wf)
{
  int t = blockIdx.x * 256 + threadIdx.x;   // 0..12287
  int j    = t & 7;
  int lane = (t >> 3) & 63;
  int kt   = (t >> 9) & 3;
  int n6   = t >> 11;
  int k    = kt * 32 + (lane >> 4) * 8 + j;
  int col  = (n6 & 1) * 16 + (lane & 15);
  const float* W = (n6 >> 1) == 0 ? Wq : ((n6 >> 1) == 1 ? Wk : Wv);
  wf[t] = (bf16_t)W[k * HD + col];
}

__global__ __launch_bounds__(256) void head_fused(
    const float* __restrict__ x, const bf8_t* __restrict__ wf,
    float* __restrict__ out)
{
  // LDS: 17408 + 5120 + 5120 + 4608 = 32256 B -> 5 blocks/CU.
  __shared__ __align__(16) bf16_t xs[TT][136];   // x tile; aliased as ps[64][72] later
  __shared__ __align__(16) bf16_t qs[TT][40];    // q[row][d]
  __shared__ __align__(16) bf16_t ks[TT][40];    // k[row][d]  (B-frag source for QK^T)
  __shared__ __align__(16) bf16_t vt[HD][72];    // v^T[d][row] (B-frag source for PV)

  const int tid  = threadIdx.x;
  const int wave = tid >> 6;
  const int lane = tid & 63;
  const int quad = lane >> 4;
  const int l16  = lane & 15;
  const int b    = blockIdx.x;

  // ---------------- Phase 1: stage x (fp32->bf16) into LDS ----------------
  const float4* x4 = (const float4*)(x + (size_t)b * (TT * CC));
  #pragma unroll
  for (int i = 0; i < 8; ++i) {
    int e = tid + i * 256;                 // 2048 float4, coalesced
    float4 f = x4[e];
    int fi = e << 2;
    int row = fi >> 7, col = fi & 127;
    bf4_t h = { (bf16_t)f.x, (bf16_t)f.y, (bf16_t)f.z, (bf16_t)f.w };
    *(bf4_t*)&xs[row][col] = h;
  }
  __syncthreads();

  // ---------------- Phase 2: qkv = x @ [Wq|Wk|Wv], B-frags from global ----------------
  f4_t zero4 = {0.f, 0.f, 0.f, 0.f};
  f4_t acc[6];
  #pragma unroll
  for (int n = 0; n < 6; ++n) acc[n] = zero4;
  #pragma unroll
  for (int kk = 0; kk < 4; ++kk) {
    int k0 = kk * 32 + quad * 8;
    bf8_t a = *(const bf8_t*)&xs[wave * 16 + l16][k0];
    #pragma unroll
    for (int n = 0; n < 6; ++n) {
      bf8_t bb = wf[(n * 4 + kk) * 64 + lane];   // coalesced 16 B/lane, L2-hot
      acc[n] = __builtin_amdgcn_mfma_f32_16x16x32_bf16(a, bb, acc[n], 0, 0, 0);
    }
  }
  #pragma unroll
  for (int r = 0; r < 4; ++r) {
    int row = wave * 16 + quad * 4 + r;    // C/D: row = quad*4 + reg
    qs[row][l16]      = (bf16_t)acc[0][r];
    qs[row][16 + l16] = (bf16_t)acc[1][r];
    ks[row][l16]      = (bf16_t)acc[2][r];
    ks[row][16 + l16] = (bf16_t)acc[3][r];
    vt[l16][row]      = (bf16_t)acc[4][r];   // v stored transposed for PV B-frags
    vt[16 + l16][row] = (bf16_t)acc[5][r];
  }
  __syncthreads();

  // ---------------- Phase 3: S = QK^T * scale, causal softmax -> P ----------------
  bf16_t (*ps)[72] = (bf16_t(*)[72])&xs[0][0];   // alias: x tile dead now
  f4_t sc[4];
  #pragma unroll
  for (int nt = 0; nt < 4; ++nt) sc[nt] = zero4;
  {
    bf8_t aq = *(const bf8_t*)&qs[wave * 16 + l16][quad * 8];  // K=32 = one mfma
    #pragma unroll
    for (int nt = 0; nt < 4; ++nt) {
      if (nt <= wave) {                    // causal: skip fully-masked tiles
        bf8_t bk = *(const bf8_t*)&ks[nt * 16 + l16][quad * 8];
        sc[nt] = __builtin_amdgcn_mfma_f32_16x16x32_bf16(aq, bk, zero4, 0, 0, 0);
      }
    }
  }
  const float scale = 0.17677669529663687f;      // 1/sqrt(32)
  #pragma unroll
  for (int r = 0; r < 4; ++r) {
    int rl = quad * 4 + r;
    float vals[4];
    float vmax = -INFINITY;
    #pragma unroll
    for (int nt = 0; nt < 4; ++nt) {
      float v_ = -INFINITY;
      if (nt < wave)                         v_ = sc[nt][r] * scale;
      else if (nt == wave && l16 <= rl)      v_ = sc[nt][r] * scale;  // diagonal mask
      vals[nt] = v_;
      vmax = fmaxf(vmax, v_);
    }
    #pragma unroll
    for (int off = 1; off < 16; off <<= 1)
      vmax = fmaxf(vmax, __shfl_xor(vmax, off));
    float psum = 0.f;
    #pragma unroll
    for (int nt = 0; nt < 4; ++nt) {
      float p = (vals[nt] == -INFINITY) ? 0.f : __expf(vals[nt] - vmax);
      vals[nt] = p;
      psum += p;
    }
    #pragma unroll
    for (int off = 1; off < 16; off <<= 1)
      psum += __shfl_xor(psum, off);
    float inv = 1.0f / psum;
    int row = wave * 16 + rl;
    #pragma unroll
    for (int nt = 0; nt < 4; ++nt)
      ps[row][nt * 16 + l16] = (bf16_t)(vals[nt] * inv);
  }
  __syncthreads();

  // ---------------- Phase 4: O = P @ V ----------------
  f4_t o0 = zero4, o1 = zero4;
  #pragma unroll
  for (int kk = 0; kk < 2; ++kk) {
    int k0 = kk * 32 + quad * 8;
    bf8_t ap  = *(const bf8_t*)&ps[wave * 16 + l16][k0];
    bf8_t bv0 = *(const bf8_t*)&vt[l16][k0];
    bf8_t bv1 = *(const bf8_t*)&vt[16 + l16][k0];
    o0 = __builtin_amdgcn_mfma_f32_16x16x32_bf16(ap, bv0, o0, 0, 0, 0);
    o1 = __builtin_amdgcn_mfma_f32_16x16x32_bf16(ap, bv1, o1, 0, 0, 0);
  }
  float* ob = out + (size_t)b * (TT * HD);
  #pragma unroll
  for (int r = 0; r < 4; ++r) {
    int row = wave * 16 + quad * 4 + r;
    ob[row * HD + l16]      = o0[r];
    ob[row * HD + 16 + l16] = o1[r];
  }
}

extern "C" void kernel_launch(void* const* d_in, const int* in_sizes, int n_in,
                              void* d_out, int out_size, void* d_ws, size_t ws_size,
                              hipStream_t stream) {
  const float* x  = (const float*)d_in[0];
  const float* Wq = (const float*)d_in[1];
  const float* Wk = (const float*)d_in[2];
  const float* Wv = (const float*)d_in[3];
  float* out = (float*)d_out;
  bf16_t* wf = (bf16_t*)d_ws;              // 12288 bf16 = 24 KB
  int B = in_sizes[0] / (TT * CC);         // 4096

  prep_weights<<<dim3(48), dim3(256), 0, stream>>>(Wq, Wk, Wv, wf);
  head_fused<<<dim3(B), dim3(256), 0, stream>>>(x, (const bf8_t*)wf, out);
}

// Round 3
// 218.419 us; speedup vs baseline: 1.0393x; 1.0027x over previous
//
#include <hip/hip_runtime.h>

// Head: fused single-head causal attention.
// Round 3: ZERO barriers. One wave per batch element (64-thr blocks, grid=4096).
// A wave computes its whole 64-token head; layout transforms round-trip through
// block-private LDS (same-wave DS is in-order; compiler inserts lgkmcnt waits).
// x is loaded global->A-frag directly (full 128B cache lines), read exactly once.
// LDS 17152 B/block -> 9 one-wave blocks/CU, all independent streams.
//
// mfma_f32_16x16x32_bf16 layouts (HW-verified, guide §3):
//   A-frag: A[m = lane&15][k = quad*8 + j]   (8 contiguous bf16 per lane)
//   B-frag: B[k = quad*8 + j][n = lane&15]   (n-major source, k-contiguous)
//   C/D   : col = lane&15, row = quad*4 + reg

#define TT 64
#define CC 128
#define HD 32

typedef __bf16 bf16_t;
typedef __bf16 bf8_t __attribute__((ext_vector_type(8)));
typedef float  f4_t  __attribute__((ext_vector_type(4)));

// d_ws layout: wf[(n6*4 + kk)*64 + lane] is one 16-byte bf8 B-frag.
// n6 = 0..5 (q lo/hi, k lo/hi, v lo/hi 16-col tiles), kk = 0..3 (K blocks of 32).
// Element j = Wsel[(kk*32 + (lane>>4)*8 + j)][(n6&1)*16 + (lane&15)].
__global__ __launch_bounds__(256) void prep_weights(
    const float* __restrict__ Wq, const float* __restrict__ Wk,
    const float* __restrict__ Wv, bf16_t* __restrict__ wf)
{
  int t = blockIdx.x * 256 + threadIdx.x;   // 0..12287
  int j    = t & 7;
  int lane = (t >> 3) & 63;
  int kt   = (t >> 9) & 3;
  int n6   = t >> 11;
  int k    = kt * 32 + (lane >> 4) * 8 + j;
  int col  = (n6 & 1) * 16 + (lane & 15);
  const float* W = (n6 >> 1) == 0 ? Wq : ((n6 >> 1) == 1 ? Wk : Wv);
  wf[t] = (bf16_t)W[k * HD + col];
}

__global__ __launch_bounds__(64, 3) void head_fused(
    const float* __restrict__ x, const bf8_t* __restrict__ wf,
    float* __restrict__ out)
{
  // Strides chosen so every b128 frag access is 16B-aligned (stride*2 % 16 == 0)
  // and <=2-way bank-aliased (free, m136).
  __shared__ __align__(16) bf16_t qs[TT][40];   // q[row][d]        5120 B
  __shared__ __align__(16) bf16_t ks[TT][40];   // k[row][d]        5120 B
  __shared__ __align__(16) bf16_t vt[HD][72];   // v^T[d][row]      4608 B
  __shared__ __align__(16) bf16_t ps[16][72];   // P strip (1 tile) 2304 B
  // total 17152 B -> 9 blocks/CU

  const int lane = threadIdx.x;      // 0..63 (one wave)
  const int quad = lane >> 4;
  const int l16  = lane & 15;
  const int b    = blockIdx.x;
  const float* __restrict__ xb = x + (size_t)b * (TT * CC);
  float* __restrict__ ob = out + (size_t)b * (TT * HD);

  const f4_t zero4 = {0.f, 0.f, 0.f, 0.f};

  // ---------------- Phase 1: qkv projection, per 16-row M-tile ----------------
  #pragma unroll 1
  for (int i = 0; i < 4; ++i) {
    f4_t acc[6];
    #pragma unroll
    for (int n = 0; n < 6; ++n) acc[n] = zero4;
    #pragma unroll
    for (int kk = 0; kk < 4; ++kk) {
      // A-frag of x straight from global: lane reads 8 consecutive fp32.
      // Per kk the wave covers 16 rows x 128 B contiguous -> full cache lines.
      const float* src = xb + (16 * i + l16) * CC + kk * 32 + quad * 8;
      float4 f0 = *(const float4*)(src);
      float4 f1 = *(const float4*)(src + 4);
      bf8_t a;
      a[0] = (bf16_t)f0.x; a[1] = (bf16_t)f0.y; a[2] = (bf16_t)f0.z; a[3] = (bf16_t)f0.w;
      a[4] = (bf16_t)f1.x; a[5] = (bf16_t)f1.y; a[6] = (bf16_t)f1.z; a[7] = (bf16_t)f1.w;
      #pragma unroll
      for (int n = 0; n < 6; ++n) {
        bf8_t bb = wf[(n * 4 + kk) * 64 + lane];   // L1/L2-hot, 16 B/lane
        acc[n] = __builtin_amdgcn_mfma_f32_16x16x32_bf16(a, bb, acc[n], 0, 0, 0);
      }
    }
    // C-layout -> LDS writeback (row = quad*4 + reg, col = l16)
    #pragma unroll
    for (int r = 0; r < 4; ++r) {
      int row = 16 * i + quad * 4 + r;
      qs[row][l16]      = (bf16_t)acc[0][r];
      qs[row][16 + l16] = (bf16_t)acc[1][r];
      ks[row][l16]      = (bf16_t)acc[2][r];
      ks[row][16 + l16] = (bf16_t)acc[3][r];
      vt[l16][row]      = (bf16_t)acc[4][r];   // v stored transposed for PV B-frags
      vt[16 + l16][row] = (bf16_t)acc[5][r];
    }
  }
  // No barrier: single wave; DS ops are in-order, compiler inserts lgkmcnt waits.

  // ---------------- Phase 2: per M-tile scores -> softmax -> PV -> store ----------------
  const float scale = 0.17677669529663687f;    // 1/sqrt(32)
  #pragma unroll 1
  for (int i = 0; i < 4; ++i) {
    // S_i = Q_i @ K^T (causal: only j <= i), K=32 = one MFMA per tile
    f4_t sc[4];
    bf8_t aq = *(const bf8_t*)&qs[16 * i + l16][quad * 8];
    #pragma unroll
    for (int j = 0; j < 4; ++j) {
      sc[j] = zero4;
      if (j <= i) {                            // wave-uniform branch
        bf8_t bk = *(const bf8_t*)&ks[16 * j + l16][quad * 8];
        sc[j] = __builtin_amdgcn_mfma_f32_16x16x32_bf16(aq, bk, zero4, 0, 0, 0);
      }
    }
    // causal softmax; row (local) = quad*4 + r lives in the 16 lanes of this quad
    #pragma unroll
    for (int r = 0; r < 4; ++r) {
      int rl = quad * 4 + r;
      float vals[4];
      float vmax = -INFINITY;
      #pragma unroll
      for (int j = 0; j < 4; ++j) {
        bool valid = (j < i) | ((j == i) & (l16 <= rl));
        float v_ = valid ? sc[j][r] * scale : -INFINITY;
        vals[j] = v_;
        vmax = fmaxf(vmax, v_);
      }
      #pragma unroll
      for (int off = 1; off < 16; off <<= 1)
        vmax = fmaxf(vmax, __shfl_xor(vmax, off));
      float psum = 0.f;
      #pragma unroll
      for (int j = 0; j < 4; ++j) {
        float p = (vals[j] == -INFINITY) ? 0.f : __expf(vals[j] - vmax);
        vals[j] = p;
        psum += p;
      }
      #pragma unroll
      for (int off = 1; off < 16; off <<= 1)
        psum += __shfl_xor(psum, off);
      float inv = 1.0f / psum;                 // psum >= 1 (diagonal survives)
      #pragma unroll
      for (int j = 0; j < 4; ++j)
        ps[rl][j * 16 + l16] = (bf16_t)(vals[j] * inv);  // strip-local row
    }
    // O_i = P_i @ V : P strip A-frags + v^T B-frags
    f4_t o0 = zero4, o1 = zero4;
    #pragma unroll
    for (int kk = 0; kk < 2; ++kk) {
      int k0 = kk * 32 + quad * 8;
      bf8_t ap  = *(const bf8_t*)&ps[l16][k0];
      bf8_t bv0 = *(const bf8_t*)&vt[l16][k0];
      bf8_t bv1 = *(const bf8_t*)&vt[16 + l16][k0];
      o0 = __builtin_amdgcn_mfma_f32_16x16x32_bf16(ap, bv0, o0, 0, 0, 0);
      o1 = __builtin_amdgcn_mfma_f32_16x16x32_bf16(ap, bv1, o1, 0, 0, 0);
    }
    #pragma unroll
    for (int r = 0; r < 4; ++r) {
      int row = 16 * i + quad * 4 + r;
      ob[row * HD + l16]      = o0[r];         // 64 B contiguous per 16-lane group
      ob[row * HD + 16 + l16] = o1[r];
    }
  }
}

extern "C" void kernel_launch(void* const* d_in, const int* in_sizes, int n_in,
                              void* d_out, int out_size, void* d_ws, size_t ws_size,
                              hipStream_t stream) {
  const float* x  = (const float*)d_in[0];
  const float* Wq = (const float*)d_in[1];
  const float* Wk = (const float*)d_in[2];
  const float* Wv = (const float*)d_in[3];
  float* out = (float*)d_out;
  bf16_t* wf = (bf16_t*)d_ws;                  // 12288 bf16 = 24 KB
  int B = in_sizes[0] / (TT * CC);             // 4096

  prep_weights<<<dim3(48), dim3(256), 0, stream>>>(Wq, Wk, Wv, wf);
  head_fused<<<dim3(B), dim3(64), 0, stream>>>(x, (const bf8_t*)wf, out);
}

// Round 4
// 209.520 us; speedup vs baseline: 1.0834x; 1.0425x over previous
//
#include <hip/hip_runtime.h>

// Head: fused single-head causal attention. Round 4: MLP-starvation fix.
// One wave per batch element (64-thr blocks, grid=4096), zero barriers.
// Weights register-resident (24 B-frags, loaded once); x software-pipelined
// double-buffer register prefetch (8-24 KB in flight per wave, 8 waves/CU).
// Softmax: no max-sub (|s|<~3), scale folded into Wq at prep time.
//
// mfma_f32_16x16x32_bf16 layouts (HW-verified, guide §3):
//   A-frag: A[m = lane&15][k = quad*8 + j]
//   B-frag: B[k = quad*8 + j][n = lane&15]
//   C/D   : col = lane&15, row = quad*4 + reg

#define TT 64
#define CC 128
#define HD 32

typedef __bf16 bf16_t;
typedef __bf16 bf8_t __attribute__((ext_vector_type(8)));
typedef __bf16 bf4_t __attribute__((ext_vector_type(4)));
typedef float  f4_t  __attribute__((ext_vector_type(4)));

// d_ws: wf[(n6*4 + kk)*64 + lane] = 16-byte bf8 B-frag.
// n6 = 0..5 (q lo/hi, k lo/hi, v lo/hi), kk = 0..3 (K blocks of 32).
// Element j = Wsel[(kk*32 + (lane>>4)*8 + j)][(n6&1)*16 + (lane&15)].
// Q-frags (n6<2) pre-scaled by 1/sqrt(32).
__global__ __launch_bounds__(256) void prep_weights(
    const float* __restrict__ Wq, const float* __restrict__ Wk,
    const float* __restrict__ Wv, bf16_t* __restrict__ wf)
{
  int t = blockIdx.x * 256 + threadIdx.x;   // 0..12287
  int j    = t & 7;
  int lane = (t >> 3) & 63;
  int kt   = (t >> 9) & 3;
  int n6   = t >> 11;
  int k    = kt * 32 + (lane >> 4) * 8 + j;
  int col  = (n6 & 1) * 16 + (lane & 15);
  const float* W = (n6 >> 1) == 0 ? Wq : ((n6 >> 1) == 1 ? Wk : Wv);
  float v = W[k * HD + col];
  if (n6 < 2) v *= 0.17677669529663687f;    // fold 1/sqrt(32) into Wq
  wf[t] = (bf16_t)v;
}

__global__ __launch_bounds__(64, 2) void head_fused(
    const float* __restrict__ x, const bf8_t* __restrict__ wf,
    float* __restrict__ out)
{
  __shared__ __align__(16) bf16_t qs[TT][40];   // q[row][d]        5120 B
  __shared__ __align__(16) bf16_t ks[TT][40];   // k[row][d]        5120 B
  __shared__ __align__(16) bf16_t vt[HD][72];   // v^T[d][row]      4608 B
  __shared__ __align__(16) bf16_t ps[16][72];   // P strip          2304 B
  // total 17152 B; 8 one-wave blocks/CU (VGPR-capped at 2 waves/EU)

  const int lane = threadIdx.x;      // 0..63, one wave
  const int quad = lane >> 4;
  const int l16  = lane & 15;
  const int b    = blockIdx.x;
  const float* __restrict__ xblk = x + (size_t)b * (TT * CC);
  float* __restrict__ ob = out + (size_t)b * (TT * HD);

  const f4_t zero4 = {0.f, 0.f, 0.f, 0.f};

  bf8_t wfr[24];                     // register-resident weight B-frags (96 VGPR)

  // issue x-tile loads: 8x dwordx4 per tile (lane covers 32 B of row l16)
  auto load_tile = [&](float4* d, int i) {
    #pragma unroll
    for (int kk = 0; kk < 4; ++kk) {
      const float* s = xblk + (16 * i + l16) * CC + kk * 32 + quad * 8;
      d[2 * kk]     = *(const float4*)s;
      d[2 * kk + 1] = *(const float4*)(s + 4);
    }
  };

  auto proj_tile = [&](const float4* d, int i) {
    f4_t acc[6];
    #pragma unroll
    for (int n = 0; n < 6; ++n) acc[n] = zero4;
    #pragma unroll
    for (int kk = 0; kk < 4; ++kk) {
      float4 f0 = d[2 * kk], f1 = d[2 * kk + 1];
      bf8_t a;
      a[0] = (bf16_t)f0.x; a[1] = (bf16_t)f0.y; a[2] = (bf16_t)f0.z; a[3] = (bf16_t)f0.w;
      a[4] = (bf16_t)f1.x; a[5] = (bf16_t)f1.y; a[6] = (bf16_t)f1.z; a[7] = (bf16_t)f1.w;
      #pragma unroll
      for (int n = 0; n < 6; ++n)
        acc[n] = __builtin_amdgcn_mfma_f32_16x16x32_bf16(a, wfr[n * 4 + kk], acc[n], 0, 0, 0);
    }
    #pragma unroll
    for (int r = 0; r < 4; ++r) {
      int row = 16 * i + quad * 4 + r;         // C/D: row = quad*4 + reg
      qs[row][l16]      = (bf16_t)acc[0][r];
      qs[row][16 + l16] = (bf16_t)acc[1][r];
      ks[row][l16]      = (bf16_t)acc[2][r];
      ks[row][16 + l16] = (bf16_t)acc[3][r];
    }
    bf4_t v0 = { (bf16_t)acc[4][0], (bf16_t)acc[4][1], (bf16_t)acc[4][2], (bf16_t)acc[4][3] };
    bf4_t v1 = { (bf16_t)acc[5][0], (bf16_t)acc[5][1], (bf16_t)acc[5][2], (bf16_t)acc[5][3] };
    *(bf4_t*)&vt[l16][16 * i + quad * 4]      = v0;   // tokens quad*4..+3 contiguous
    *(bf4_t*)&vt[16 + l16][16 * i + quad * 4] = v1;
  };

  // ---------------- Phase 1: pipelined projection ----------------
  float4 ta[8], tb[8];
  load_tile(ta, 0);                  // issue tile 0 first
  #pragma unroll
  for (int t = 0; t < 24; ++t) wfr[t] = wf[t * 64 + lane];   // then weights (L2/L1-hot)
  load_tile(tb, 1);                  // then tile 1: waiting on tile0+wf leaves tile1 in flight
  proj_tile(ta, 0);
  load_tile(ta, 2);                  // prefetch i+2 while computing i
  proj_tile(tb, 1);
  load_tile(tb, 3);
  proj_tile(ta, 2);
  proj_tile(tb, 3);
  // no barrier: single wave, DS ops in-order (compiler inserts lgkmcnt waits)

  // ---------------- Phase 2: scores -> softmax -> PV per M-tile ----------------
  #pragma unroll
  for (int i = 0; i < 4; ++i) {
    f4_t sc[4];
    bf8_t aq = *(const bf8_t*)&qs[16 * i + l16][quad * 8];   // scale pre-folded
    #pragma unroll
    for (int j = 0; j < 4; ++j) {
      sc[j] = zero4;
      if (j <= i) {
        bf8_t bk = *(const bf8_t*)&ks[16 * j + l16][quad * 8];
        sc[j] = __builtin_amdgcn_mfma_f32_16x16x32_bf16(aq, bk, zero4, 0, 0, 0);
      }
    }
    #pragma unroll
    for (int r = 0; r < 4; ++r) {
      int rl = quad * 4 + r;
      float p[4];
      float psum = 0.f;
      #pragma unroll
      for (int j = 0; j < 4; ++j) {
        if (j <= i) {
          // no max-sub: |s| <= ~3 analytically, exp is safe
          bool valid = (j < i) | (l16 <= rl);  // diagonal-tile causal mask
          float e = __expf(sc[j][r]);
          p[j] = valid ? e : 0.f;
          psum += p[j];
        } else p[j] = 0.f;
      }
      #pragma unroll
      for (int off = 1; off < 16; off <<= 1)
        psum += __shfl_xor(psum, off);
      float inv = __builtin_amdgcn_rcpf(psum);   // psum >= diag term > 0
      #pragma unroll
      for (int j = 0; j < 4; ++j) {
        if (j <= i)             ps[rl][j * 16 + l16] = (bf16_t)(p[j] * inv);
        else if (j == (i | 1))  ps[rl][j * 16 + l16] = (bf16_t)0.f;  // zero-fill read range
      }
    }
    f4_t o0 = zero4, o1 = zero4;
    #pragma unroll
    for (int kk = 0; kk <= (i >> 1); ++kk) {     // skip all-zero K-tiles for i<2
      int k0 = kk * 32 + quad * 8;
      bf8_t ap  = *(const bf8_t*)&ps[l16][k0];
      bf8_t bv0 = *(const bf8_t*)&vt[l16][k0];
      bf8_t bv1 = *(const bf8_t*)&vt[16 + l16][k0];
      o0 = __builtin_amdgcn_mfma_f32_16x16x32_bf16(ap, bv0, o0, 0, 0, 0);
      o1 = __builtin_amdgcn_mfma_f32_16x16x32_bf16(ap, bv1, o1, 0, 0, 0);
    }
    #pragma unroll
    for (int r = 0; r < 4; ++r) {
      int row = 16 * i + quad * 4 + r;
      ob[row * HD + l16]      = o0[r];
      ob[row * HD + 16 + l16] = o1[r];
    }
  }
}

extern "C" void kernel_launch(void* const* d_in, const int* in_sizes, int n_in,
                              void* d_out, int out_size, void* d_ws, size_t ws_size,
                              hipStream_t stream) {
  const float* x  = (const float*)d_in[0];
  const float* Wq = (const float*)d_in[1];
  const float* Wk = (const float*)d_in[2];
  const float* Wv = (const float*)d_in[3];
  float* out = (float*)d_out;
  bf16_t* wf = (bf16_t*)d_ws;                  // 12288 bf16 = 24 KB
  int B = in_sizes[0] / (TT * CC);             // 4096

  prep_weights<<<dim3(48), dim3(256), 0, stream>>>(Wq, Wk, Wv, wf);
  head_fused<<<dim3(B), dim3(64), 0, stream>>>(x, (const bf8_t*)wf, out);
}